// Round 1
// 14042.438 us; speedup vs baseline: 1.0459x; 1.0459x over previous
//
#include <hip/hip_runtime.h>

// ---------------------------------------------------------------------------
// CLIP text transformer forward, MI355X/gfx950.
// Shapes: N=64, L=77, D=768, V=8, M=8, H=12 heads (hd=64), 12 layers.
// Rows = M*N*L = 39424 = 154*256 (exact 256-row tiles).
// Round 4: GEMM rewritten as the 256x256 8-phase pipelined template
// (T2 LDS XOR-swizzle + T3/T4 counted-vmcnt 8-phase + T5 setprio + T1 XCD
// swizzle). 512 threads / 8 waves, BK=64, 128 KiB LDS double buffer,
// per-wave 128x64 output. vmcnt(6) only at phases 4/8 — loads stay in
// flight across barriers; no vmcnt(0) drain in the main loop.
// ---------------------------------------------------------------------------

typedef short short8 __attribute__((ext_vector_type(8)));
typedef float floatx4 __attribute__((ext_vector_type(4)));
typedef unsigned int uint4v __attribute__((ext_vector_type(4)));
typedef unsigned short ushort4v __attribute__((ext_vector_type(4)));

#define SOV_TOK 49408
#define EOT_TOK 49407
#define ROWS 39424      // 512*77

__device__ __forceinline__ unsigned short f2bf(float f) {
  union { float f; unsigned int u; } v; v.f = f;
  return (unsigned short)((v.u + 0x7fffu + ((v.u >> 16) & 1u)) >> 16);
}

typedef const __attribute__((address_space(1))) void* gptr_t;
typedef __attribute__((address_space(3))) void* lptr_t;
__device__ __forceinline__ void glds16(const void* g, void* l) {
  __builtin_amdgcn_global_load_lds((gptr_t)g, (lptr_t)l, 16, 0, 0);
}

__device__ __forceinline__ float blockReduceSum256(float v, float* red) {
  __syncthreads();                    // protect red reuse across calls
  #pragma unroll
  for (int off = 32; off; off >>= 1) v += __shfl_down(v, off, 64);
  int wave = threadIdx.x >> 6, lane = threadIdx.x & 63;
  if (lane == 0) red[wave] = v;
  __syncthreads();
  return red[0] + red[1] + red[2] + red[3];
}

// ---------------- index scan: first SOV / first EOT per sequence ----------
__global__ void idx_kernel(const int* text, int* posy, int* eot) {
  int n = threadIdx.x;  // 64 threads
  int py = 0, et = 0; bool fp = false, fe = false;
  for (int j = 0; j < 77; j++) {
    int v = text[n * 77 + j];
    if (!fp && v == SOV_TOK) { py = j; fp = true; }
    if (!fe && v == EOT_TOK) { et = j; fe = true; }
  }
  posy[n] = py; eot[n] = et;
}

// ---------------- fp32 -> bf16 weight conversion --------------------------
__global__ void cvt_kernel(const float* src, unsigned short* dst, int n) {
  int i = (blockIdx.x * 256 + threadIdx.x) * 4;
  if (i < n) {
    float4 v = *(const float4*)(src + i);
    ushort4v o;
    o.x = f2bf(v.x); o.y = f2bf(v.y); o.z = f2bf(v.z); o.w = f2bf(v.w);
    *(ushort4v*)(dst + i) = o;
  }
}

// transpose text_proj (D,E) -> bf16 (E,D)
__global__ void transT_kernel(const float* tp, unsigned short* wt) {
  int id = blockIdx.x * 256 + threadIdx.x;   // 768*768 total
  int d = id / 768, e = id % 768;
  wt[(size_t)e * 768 + d] = f2bf(tp[id]);
}

// ---------------- build h = splice(tok_emb, visual) + pos_emb -------------
__global__ void embed_kernel(const int* text, const float* vis,
                             const float* tok_emb, const float* pos_emb,
                             const int* posy, float* h) {
  int bp = blockIdx.x;              // 0..39423 = b*77+p
  int b = bp / 77, p = bp % 77;
  int mm = b >> 6, n = b & 63;
  int py = posy[n];
  int t = threadIdx.x;              // 192 threads * float4 = 768
  const float* srcp;
  if (p >= py && p < py + 8) {
    srcp = vis + ((size_t)mm * 8 + (p - py)) * 768;
  } else {
    int src = (p < py) ? p : p - 7;
    src = src < 0 ? 0 : (src > 76 ? 76 : src);
    int tok = text[n * 77 + src];
    srcp = tok_emb + (size_t)tok * 768;
  }
  float4 v = *(const float4*)(srcp + t * 4);
  float4 pe = *(const float4*)(pos_emb + (size_t)p * 768 + t * 4);
  v.x += pe.x; v.y += pe.y; v.z += pe.z; v.w += pe.w;
  *(float4*)(h + (size_t)bp * 768 + t * 4) = v;
}

// ---------------- row LayerNorm fp32 -> bf16 ------------------------------
__device__ __forceinline__ void ln_row(const float* xr, const float* w,
                                       const float* b, unsigned short* yr,
                                       float* red) {
  int t = threadIdx.x;  // 256
  float v0 = xr[t], v1 = xr[t + 256], v2 = xr[t + 512];
  float s = blockReduceSum256(v0 + v1 + v2, red);
  float mu = s * (1.f / 768.f);
  float d0 = v0 - mu, d1 = v1 - mu, d2 = v2 - mu;
  float q = blockReduceSum256(d0 * d0 + d1 * d1 + d2 * d2, red);
  float rstd = rsqrtf(q * (1.f / 768.f) + 1e-5f);
  yr[t]       = f2bf(d0 * rstd * w[t]       + b[t]);
  yr[t + 256] = f2bf(d1 * rstd * w[t + 256] + b[t + 256]);
  yr[t + 512] = f2bf(d2 * rstd * w[t + 512] + b[t + 512]);
}

__global__ void ln_kernel(const float* x, const float* w, const float* b,
                          unsigned short* y) {
  __shared__ float red[4];
  size_t r = blockIdx.x;
  ln_row(x + r * 768, w, b, y + r * 768, red);
}

// gather the (eot+V-1) token per (m,n) and apply final LN
__global__ void gather_ln_kernel(const float* h, const int* eot,
                                 const float* w, const float* b,
                                 unsigned short* y) {
  __shared__ float red[4];
  int r = blockIdx.x;               // 0..511 = m*64+n
  int n = r & 63;
  size_t row = (size_t)r * 77 + (eot[n] + 7);
  ln_row(h + row * 768, w, b, y + (size_t)r * 768, red);
}

// ---------------------------------------------------------------------------
// GEMM: C[rows,cols] = A_bf16[rows,K] @ W_bf16[cols,K]^T
// 256x256 tile, BK=64, 8 waves (2Mx4N), 8-phase counted-vmcnt schedule.
// MODE 0: +bias -> bf16    MODE 1: gelu(+bias) -> bf16
// MODE 2: h += (+bias), fp32 in/out    MODE 3: (+bias?) -> fp32
//
// LDS layout (per operand, per buffer): 256 rows x 64 bf16, but rows are
// PERMUTED so each wave-quadrant's read-rows form a contiguous 128-row
// stageable half, and each row's 128B is XOR-swizzled by (row&7)<<4 bytes
// (applied on the pre-swizzled global source, since global_load_lds writes
// linearly).  A: LDS row (h*128 + r*64 + lr) holds global row lr+h*64+r*128.
//             B: LDS row (h*128 + r*64 + lr) holds global row
//                (lr&31) + ((lr>>5)&1)*64 + h*32 + r*128.
// Stage schedule per 8-phase iteration (tiles T=2i buf0, T+1 buf1):
//   p1:B1h0(T+1)  p2:A0h0(T+2) p3:B0h1(T+2) p4:A0h1(T+2)+vmcnt(6)
//   p5:B0h0(T+2)  p6:A1h0(T+3) p7:B1h1(T+3) p8:A1h1(T+3)+vmcnt(6)
// Each stage targets the region whose last ds_read was the previous phase;
// vmcnt(6) = 2 loads/half-tile x 3 half-tiles in flight.  K-tail prefetches
// are clamped to the last tile (keeps vmcnt counts invariant; the garbage
// lands in already-consumed LDS and is never read).
// ---------------------------------------------------------------------------
template <int MODE>
__global__ __launch_bounds__(512, 2)
void gemm256_kernel(const unsigned short* __restrict__ A,
                    const unsigned short* __restrict__ W,
                    const float* __restrict__ bias, void* __restrict__ outp,
                    const float* __restrict__ resid, int K, int cols) {
  __shared__ __align__(16) unsigned short As[2][16384];   // 2 x 32 KiB
  __shared__ __align__(16) unsigned short Bs[2][16384];   // 2 x 32 KiB

  const int gx = gridDim.x;
  const int G = gx * gridDim.y;
  const int P = blockIdx.y * gx + blockIdx.x;
  // bijective XCD swizzle (m204 form; handles G%8 != 0)
  const int q8 = G >> 3, r8 = G & 7;
  const int xcd = P & 7, ord = P >> 3;
  const int Lid =
      (xcd < r8 ? xcd * (q8 + 1) : r8 * (q8 + 1) + (xcd - r8) * q8) + ord;
  const int col0 = (Lid % gx) * 256;
  const int row0 = (Lid / gx) * 256;

  const int t = threadIdx.x;
  const int wave = t >> 6, lane = t & 63;
  const int m = lane & 15, quad = lane >> 4;
  const int wm = wave >> 2, wn = wave & 3;

  // ---- staging addresses: thread t stages 16B at LDS linear o=t*16 (+8KB
  // for round 1).  lr0 = LDS row within 64-row round; source column is the
  // XOR-swizzled chunk so a swizzled ds_read retrieves linear data.
  const int lr0 = t >> 3;                                    // 0..63
  const int cbe = ((t & 7) << 3) ^ ((lr0 & 7) << 3);         // elems in row
  const unsigned short* Abase = A + (size_t)(row0 + lr0) * K + cbe;
  const int grB0 = (lr0 & 31) + ((lr0 >> 5) << 6);
  const unsigned short* Bbase = W + (size_t)(col0 + grB0) * K + cbe;

#define STAGE_A(b, h, kb) {                                                  \
    const unsigned short* _p = Abase + (size_t)(h) * 64 * K + (kb);          \
    glds16(_p, &As[b][(h) * 8192 + wave * 512]);                             \
    glds16(_p + (size_t)128 * K, &As[b][(h) * 8192 + 4096 + wave * 512]); }
#define STAGE_B(b, h, kb) {                                                  \
    const unsigned short* _p = Bbase + (size_t)(h) * 32 * K + (kb);          \
    glds16(_p, &Bs[b][(h) * 8192 + wave * 512]);                             \
    glds16(_p + (size_t)128 * K, &Bs[b][(h) * 8192 + 4096 + wave * 512]); }

  // ---- fragment reads (swizzled): row = h*128 + waveRow + frag*16 + m
  const int aRow = wm * 64 + m;
  const int bRow = wn * 32 + m;
  const int sw = (m & 7) << 3;
  short8 af[4][2], bfr[2][2];
  floatx4 acc[8][4] = {};

#define RD_A(b, ha) {                                                        \
    _Pragma("unroll") for (int fi = 0; fi < 4; ++fi)                         \
    _Pragma("unroll") for (int ks = 0; ks < 2; ++ks)                         \
      af[fi][ks] = *(const short8*)&As[b][((ha) * 128 + aRow + fi * 16) * 64 \
                                          + (((ks << 5) | (quad << 3)) ^ sw)]; }
#define RD_B(b, hb) {                                                        \
    _Pragma("unroll") for (int fj = 0; fj < 2; ++fj)                         \
    _Pragma("unroll") for (int ks = 0; ks < 2; ++ks)                         \
      bfr[fj][ks] = *(const short8*)&Bs[b][((hb) * 128 + bRow + fj * 16) * 64\
                                          + (((ks << 5) | (quad << 3)) ^ sw)]; }
#define MFMA16(AH, BH) {                                                     \
    __builtin_amdgcn_s_setprio(1);                                           \
    _Pragma("unroll") for (int fi = 0; fi < 4; ++fi)                         \
    _Pragma("unroll") for (int fj = 0; fj < 2; ++fj)                         \
    _Pragma("unroll") for (int ks = 0; ks < 2; ++ks)                         \
      acc[(AH) * 4 + fi][(BH) * 2 + fj] =                                    \
          __builtin_amdgcn_mfma_f32_16x16x32_bf16(                           \
              af[fi][ks], bfr[fj][ks], acc[(AH) * 4 + fi][(BH) * 2 + fj],    \
              0, 0, 0);                                                      \
    __builtin_amdgcn_s_setprio(0); }
#define SBZ() __builtin_amdgcn_sched_barrier(0)
#define BAR() { SBZ(); __builtin_amdgcn_s_barrier(); SBZ(); }
#define WLDS() { asm volatile("s_waitcnt lgkmcnt(0)" ::: "memory"); SBZ(); }
#define WVM6() { asm volatile("s_waitcnt vmcnt(6)" ::: "memory"); SBZ(); }

  const int NT = K >> 6;        // 64-wide K tiles (12 or 48; always even)
  const int NI = NT >> 1;

  // prologue: tile0 complete (8 loads) + tile1 {A h0, B h1, A h1} (6 loads)
  STAGE_A(0, 0, 0); STAGE_A(0, 1, 0); STAGE_B(0, 0, 0); STAGE_B(0, 1, 0);
  STAGE_A(1, 0, 64); STAGE_B(1, 1, 64); STAGE_A(1, 1, 64);
  WVM6();            // tile0 landed; tile1's 6 loads may remain in flight
  BAR();

  for (int i = 0; i < NI; ++i) {
    const int T = i << 1;
    const int k1 = (T + 1) << 6;
    const int k2 = (T + 2 < NT ? T + 2 : NT - 1) << 6;
    const int k3 = (T + 3 < NT ? T + 3 : NT - 1) << 6;
    // ---- tile T (buf0), quadrant order (A0,B0)(A0,B1)(A1,B1)(A1,B0)
    // p1
    RD_A(0, 0); RD_B(0, 0); STAGE_B(1, 0, k1);
    BAR(); WLDS(); MFMA16(0, 0); BAR();
    // p2
    RD_B(0, 1); STAGE_A(0, 0, k2);
    BAR(); WLDS(); MFMA16(0, 1); BAR();
    // p3
    RD_A(0, 1); STAGE_B(0, 1, k2);
    BAR(); WLDS(); MFMA16(1, 1); BAR();
    // p4
    RD_B(0, 0); STAGE_A(0, 1, k2); WVM6();
    BAR(); WLDS(); MFMA16(1, 0); BAR();
    // ---- tile T+1 (buf1)
    // p5
    RD_A(1, 0); RD_B(1, 0); STAGE_B(0, 0, k2);
    BAR(); WLDS(); MFMA16(0, 0); BAR();
    // p6
    RD_B(1, 1); STAGE_A(1, 0, k3);
    BAR(); WLDS(); MFMA16(0, 1); BAR();
    // p7
    RD_A(1, 1); STAGE_B(1, 1, k3);
    BAR(); WLDS(); MFMA16(1, 1); BAR();
    // p8
    RD_B(1, 0); STAGE_A(1, 1, k3); WVM6();
    BAR(); WLDS(); MFMA16(1, 0); BAR();
  }
  asm volatile("s_waitcnt vmcnt(0)" ::: "memory");  // drain tail prefetches

  // epilogue: C/D layout col = lane&15, row = quad*4+reg
  const int crow = row0 + wm * 128 + quad * 4;
  const int ccol = col0 + wn * 64 + m;
  #pragma unroll
  for (int fi = 0; fi < 8; ++fi) {
    #pragma unroll
    for (int fj = 0; fj < 4; ++fj) {
      const int c = ccol + fj * 16;
      const float bi = bias ? bias[c] : 0.f;
      const int rb = crow + fi * 16;
      #pragma unroll
      for (int reg = 0; reg < 4; ++reg) {
        const size_t idx = (size_t)(rb + reg) * cols + c;
        float v = acc[fi][fj][reg] + bi;
        if (MODE == 0) {
          ((unsigned short*)outp)[idx] = f2bf(v);
        } else if (MODE == 1) {
          float g = v / (1.f + __expf(-1.702f * v));
          ((unsigned short*)outp)[idx] = f2bf(g);
        } else if (MODE == 2) {
          ((float*)outp)[idx] = resid[idx] + v;
        } else {
          ((float*)outp)[idx] = v;
        }
      }
    }
  }
#undef STAGE_A
#undef STAGE_B
#undef RD_A
#undef RD_B
#undef MFMA16
#undef SBZ
#undef BAR
#undef WLDS
#undef WVM6
}

// ---------------- fused attention per (batch, head) -----------------------
// QK^T via MFMA (lower-triangular tiles only), fp32 softmax, P@V via MFMA.
__global__ __launch_bounds__(256)
void attn_kernel(const unsigned short* qkv, unsigned short* o) {
  __shared__ __align__(16) union U {
    struct { unsigned short Qs[80 * 64]; unsigned short Ks[80 * 64]; } qk;
    unsigned short Ps[80 * 96];
  } u;
  __shared__ __align__(16) unsigned short Vt[64 * 96];
  __shared__ float S[80 * 81];     // stride 81: bank-conflict-free rows

  int b = blockIdx.x, hh = blockIdx.y;
  int t = threadIdx.x, wave = t >> 6, lane = t & 63;
  int m = lane & 15, quad = lane >> 4;
  const unsigned short* base = qkv + (size_t)b * 77 * 2304 + hh * 64;

  // stage Q,K rows (pad rows 77..79 with zeros)
  for (int c = t; c < 640; c += 256) {
    int l = c >> 3, kc = (c & 7) * 8;
    uint4v q = {0, 0, 0, 0}, k = {0, 0, 0, 0};
    if (l < 77) {
      q = *(const uint4v*)(base + (size_t)l * 2304 + kc);
      k = *(const uint4v*)(base + (size_t)l * 2304 + 768 + kc);
    }
    *(uint4v*)(u.qk.Qs + l * 64 + kc) = q;
    *(uint4v*)(u.qk.Ks + l * 64 + kc) = k;
  }
  // stage V transposed: Vt[d][l], l padded to 96
  for (int c = t; c < 768; c += 256) {
    int l = c >> 3, d0 = (c & 7) * 8;
    union { uint4v v; unsigned short s[8]; } vv;
    vv.v = (uint4v){0, 0, 0, 0};
    if (l < 77) vv.v = *(const uint4v*)(base + (size_t)l * 2304 + 1536 + d0);
    #pragma unroll
    for (int j = 0; j < 8; j++) Vt[(d0 + j) * 96 + l] = vv.s[j];
  }
  __syncthreads();

  // S = Q K^T : lower-triangular 16x16 tiles (15 of 25)
  for (int idx = wave; idx < 15; idx += 4) {
    int ti = 0, a2 = 0;
    while (a2 + ti + 1 <= idx) { a2 += ti + 1; ti++; }
    int tj = idx - a2;
    floatx4 sa = {};
    #pragma unroll
    for (int k0 = 0; k0 < 64; k0 += 32) {
      short8 aq = *(const short8*)(u.qk.Qs + (ti * 16 + m) * 64 + k0 + quad * 8);
      short8 bk = *(const short8*)(u.qk.Ks + (tj * 16 + m) * 64 + k0 + quad * 8);
      sa = __builtin_amdgcn_mfma_f32_16x16x32_bf16(aq, bk, sa, 0, 0, 0);
    }
    #pragma unroll
    for (int r = 0; r < 4; r++)
      S[(ti * 16 + quad * 4 + r) * 81 + tj * 16 + m] = sa[r];
  }
  __syncthreads();

  // causal softmax row-per-thread (scale 1/8), write P bf16 (96-padded)
  if (t < 80) {
    int r = t;
    if (r < 77) {
      float mx = -1e30f;
      for (int j = 0; j <= r; j++) mx = fmaxf(mx, S[r * 81 + j]);
      float sum = 0.f;
      for (int j = 0; j <= r; j++) {
        float e = __expf((S[r * 81 + j] - mx) * 0.125f);
        S[r * 81 + j] = e; sum += e;
      }
      float inv = 1.f / sum;
      for (int j = 0; j < 96; j++)
        u.Ps[r * 96 + j] = (j <= r) ? f2bf(S[r * 81 + j] * inv) : (unsigned short)0;
    } else {
      for (int j = 0; j < 96; j++) u.Ps[r * 96 + j] = 0;
    }
  }
  __syncthreads();

  // O = P @ V : 5x4 tiles, K padded to 96
  for (int idx = wave; idx < 20; idx += 4) {
    int ti = idx >> 2, tj = idx & 3;
    floatx4 oa = {};
    #pragma unroll
    for (int k0 = 0; k0 < 96; k0 += 32) {
      short8 ap = *(const short8*)(u.Ps + (ti * 16 + m) * 96 + k0 + quad * 8);
      short8 bv = *(const short8*)(Vt + (tj * 16 + m) * 96 + k0 + quad * 8);
      oa = __builtin_amdgcn_mfma_f32_16x16x32_bf16(ap, bv, oa, 0, 0, 0);
    }
    #pragma unroll
    for (int r = 0; r < 4; r++) {
      int l = ti * 16 + quad * 4 + r;
      if (l < 77)
        o[((size_t)b * 77 + l) * 768 + hh * 64 + tj * 16 + m] = f2bf(oa[r]);
    }
  }
}

// ---------------- final: per-row normalize, mean over n, renormalize ------
__global__ void reduce_kernel(const float* feats, float* out) {
  __shared__ float red[4];
  int mfig = blockIdx.x;   // 0..7
  int t = threadIdx.x;     // 256
  float a0 = 0.f, a1 = 0.f, a2 = 0.f;
  for (int n = 0; n < 64; n++) {
    const float* fr = feats + ((size_t)mfig * 64 + n) * 768;
    float v0 = fr[t], v1 = fr[t + 256], v2 = fr[t + 512];
    float q = blockReduceSum256(v0 * v0 + v1 * v1 + v2 * v2, red);
    float rn = rsqrtf(q);
    a0 += v0 * rn; a1 += v1 * rn; a2 += v2 * rn;
  }
  float q = blockReduceSum256(a0 * a0 + a1 * a1 + a2 * a2, red);
  float rn = rsqrtf(q);
  out[mfig * 768 + t]       = a0 * rn;
  out[mfig * 768 + t + 256] = a1 * rn;
  out[mfig * 768 + t + 512] = a2 * rn;
}

// ---------------------------------------------------------------------------
extern "C" void kernel_launch(void* const* d_in, const int* in_sizes, int n_in,
                              void* d_out, int out_size, void* d_ws,
                              size_t ws_size, hipStream_t stream) {
  (void)in_sizes; (void)n_in; (void)out_size; (void)ws_size;
  const int*   text      = (const int*)d_in[0];
  const float* visf      = (const float*)d_in[1];
  const float* tok_emb   = (const float*)d_in[2];
  const float* pos_emb   = (const float*)d_in[3];
  const float* ln1_w     = (const float*)d_in[4];
  const float* ln1_b     = (const float*)d_in[5];
  const float* in_w      = (const float*)d_in[6];
  const float* in_b      = (const float*)d_in[7];
  const float* out_w     = (const float*)d_in[8];
  const float* out_b     = (const float*)d_in[9];
  const float* ln2_w     = (const float*)d_in[10];
  const float* ln2_b     = (const float*)d_in[11];
  const float* fc_w      = (const float*)d_in[12];
  const float* fc_b      = (const float*)d_in[13];
  const float* pj_w      = (const float*)d_in[14];
  const float* pj_b      = (const float*)d_in[15];
  const float* lnf_w     = (const float*)d_in[16];
  const float* lnf_b     = (const float*)d_in[17];
  const float* text_proj = (const float*)d_in[18];
  float* out = (float*)d_out;

  char* p = (char*)d_ws;
  auto alloc = [&](size_t bytes) {
    char* q = p; p += (bytes + 255) & ~(size_t)255; return q;
  };
  int* posy = (int*)alloc(64 * 4);
  int* eot  = (int*)alloc(64 * 4);
  float* h            = (float*)alloc((size_t)ROWS * 768 * 4);          // 121 MB
  unsigned short* y   = (unsigned short*)alloc((size_t)ROWS * 768 * 2); // 61 MB
  unsigned short* qkv = (unsigned short*)alloc((size_t)ROWS * 2304 * 2);// 182 MB
  unsigned short* ob  = (unsigned short*)alloc((size_t)ROWS * 768 * 2); // 61 MB
  unsigned short* act = qkv;  // aliases qkv+ob (dead when act is live)
  // per-layer bf16 weight buffer (reused each layer; stream-ordered)
  unsigned short* wqkv = (unsigned short*)alloc((size_t)2304 * 768 * 2);
  unsigned short* wout = (unsigned short*)alloc((size_t)768 * 768 * 2);
  unsigned short* wfc  = (unsigned short*)alloc((size_t)3072 * 768 * 2);
  unsigned short* wpj  = (unsigned short*)alloc((size_t)768 * 3072 * 2);
  unsigned short* wt   = (unsigned short*)alloc((size_t)768 * 768 * 2);
  unsigned short* afin = (unsigned short*)alloc((size_t)512 * 768 * 2);
  float* feats = (float*)alloc((size_t)512 * 768 * 4);

  idx_kernel<<<1, 64, 0, stream>>>(text, posy, eot);
  transT_kernel<<<(768 * 768) / 256, 256, 0, stream>>>(text_proj, wt);
  embed_kernel<<<ROWS, 192, 0, stream>>>(text, visf, tok_emb, pos_emb, posy, h);

  const int NQKV = 2304 * 768, NOUT = 768 * 768, NFC = 3072 * 768;
  for (int l = 0; l < 12; l++) {
    cvt_kernel<<<NQKV / 1024, 256, 0, stream>>>(in_w + (size_t)l * NQKV, wqkv, NQKV);
    cvt_kernel<<<NOUT / 1024, 256, 0, stream>>>(out_w + (size_t)l * NOUT, wout, NOUT);
    cvt_kernel<<<NFC / 1024, 256, 0, stream>>>(fc_w + (size_t)l * NFC, wfc, NFC);
    cvt_kernel<<<NFC / 1024, 256, 0, stream>>>(pj_w + (size_t)l * NFC, wpj, NFC);

    ln_kernel<<<ROWS, 256, 0, stream>>>(h, ln1_w + l * 768, ln1_b + l * 768, y);
    gemm256_kernel<0><<<dim3(9, 154), 512, 0, stream>>>(
        y, wqkv, in_b + l * 2304, qkv, nullptr, 768, 2304);
    attn_kernel<<<dim3(512, 12), 256, 0, stream>>>(qkv, ob);
    gemm256_kernel<2><<<dim3(3, 154), 512, 0, stream>>>(
        ob, wout, out_b + l * 768, h, h, 768, 768);
    ln_kernel<<<ROWS, 256, 0, stream>>>(h, ln2_w + l * 768, ln2_b + l * 768, y);
    gemm256_kernel<1><<<dim3(12, 154), 512, 0, stream>>>(
        y, wfc, fc_b + l * 3072, act, nullptr, 768, 3072);
    gemm256_kernel<2><<<dim3(3, 154), 512, 0, stream>>>(
        act, wpj, pj_b + l * 768, h, h, 3072, 768);
  }

  gather_ln_kernel<<<512, 256, 0, stream>>>(h, eot, lnf_w, lnf_b, afin);
  gemm256_kernel<3><<<dim3(3, 2), 512, 0, stream>>>(
      afin, wt, nullptr, feats, nullptr, 768, 768);
  reduce_kernel<<<8, 256, 0, stream>>>(feats, out);
}

// Round 2
// 12300.349 us; speedup vs baseline: 1.1940x; 1.1416x over previous
//
#include <hip/hip_runtime.h>

// ---------------------------------------------------------------------------
// CLIP text transformer forward, MI355X/gfx950.
// Shapes: N=64, L=77, D=768, V=8, M=8, H=12 heads (hd=64), 12 layers.
// Rows = M*N*L = 39424 = 154*256 (exact 256-row tiles).
// Round 5: keep the 256x256 8-phase pipelined main loop (T2 swizzle +
// T3/T4 counted vmcnt + T5 setprio + T1 XCD swizzle); rewrite the GEMM
// epilogue as an LDS-staged transpose so all global I/O is coalesced:
//   - each wave dumps its 128x64 fp32 tile (bias/GELU applied) into a
//     PRIVATE 64x68 LDS slab (2 halves), XOR-swizzled for bank-cleanliness
//   - reads back 4-row quads -> 16B-per-lane vector loads/stores
//   - MODE0/1: dwordx2 bf16 stores (was 128 scalar 2B scatters/thread)
//   - MODE2/3: float4 resid loads + float4 stores (was 4B scatters)
// LDS = union(main 128KB, epilogue slabs 136KB) -> still 1 block/CU.
// ---------------------------------------------------------------------------

typedef short short8 __attribute__((ext_vector_type(8)));
typedef float floatx4 __attribute__((ext_vector_type(4)));
typedef unsigned int uint4v __attribute__((ext_vector_type(4)));
typedef unsigned short ushort4v __attribute__((ext_vector_type(4)));

#define SOV_TOK 49408
#define EOT_TOK 49407
#define ROWS 39424      // 512*77

__device__ __forceinline__ unsigned short f2bf(float f) {
  union { float f; unsigned int u; } v; v.f = f;
  return (unsigned short)((v.u + 0x7fffu + ((v.u >> 16) & 1u)) >> 16);
}

typedef const __attribute__((address_space(1))) void* gptr_t;
typedef __attribute__((address_space(3))) void* lptr_t;
__device__ __forceinline__ void glds16(const void* g, void* l) {
  __builtin_amdgcn_global_load_lds((gptr_t)g, (lptr_t)l, 16, 0, 0);
}

__device__ __forceinline__ float blockReduceSum256(float v, float* red) {
  __syncthreads();                    // protect red reuse across calls
  #pragma unroll
  for (int off = 32; off; off >>= 1) v += __shfl_down(v, off, 64);
  int wave = threadIdx.x >> 6, lane = threadIdx.x & 63;
  if (lane == 0) red[wave] = v;
  __syncthreads();
  return red[0] + red[1] + red[2] + red[3];
}

// ---------------- index scan: first SOV / first EOT per sequence ----------
__global__ void idx_kernel(const int* text, int* posy, int* eot) {
  int n = threadIdx.x;  // 64 threads
  int py = 0, et = 0; bool fp = false, fe = false;
  for (int j = 0; j < 77; j++) {
    int v = text[n * 77 + j];
    if (!fp && v == SOV_TOK) { py = j; fp = true; }
    if (!fe && v == EOT_TOK) { et = j; fe = true; }
  }
  posy[n] = py; eot[n] = et;
}

// ---------------- fp32 -> bf16 weight conversion --------------------------
__global__ void cvt_kernel(const float* src, unsigned short* dst, int n) {
  int i = (blockIdx.x * 256 + threadIdx.x) * 4;
  if (i < n) {
    float4 v = *(const float4*)(src + i);
    ushort4v o;
    o.x = f2bf(v.x); o.y = f2bf(v.y); o.z = f2bf(v.z); o.w = f2bf(v.w);
    *(ushort4v*)(dst + i) = o;
  }
}

// transpose text_proj (D,E) -> bf16 (E,D)
__global__ void transT_kernel(const float* tp, unsigned short* wt) {
  int id = blockIdx.x * 256 + threadIdx.x;   // 768*768 total
  int d = id / 768, e = id % 768;
  wt[(size_t)e * 768 + d] = f2bf(tp[id]);
}

// ---------------- build h = splice(tok_emb, visual) + pos_emb -------------
__global__ void embed_kernel(const int* text, const float* vis,
                             const float* tok_emb, const float* pos_emb,
                             const int* posy, float* h) {
  int bp = blockIdx.x;              // 0..39423 = b*77+p
  int b = bp / 77, p = bp % 77;
  int mm = b >> 6, n = b & 63;
  int py = posy[n];
  int t = threadIdx.x;              // 192 threads * float4 = 768
  const float* srcp;
  if (p >= py && p < py + 8) {
    srcp = vis + ((size_t)mm * 8 + (p - py)) * 768;
  } else {
    int src = (p < py) ? p : p - 7;
    src = src < 0 ? 0 : (src > 76 ? 76 : src);
    int tok = text[n * 77 + src];
    srcp = tok_emb + (size_t)tok * 768;
  }
  float4 v = *(const float4*)(srcp + t * 4);
  float4 pe = *(const float4*)(pos_emb + (size_t)p * 768 + t * 4);
  v.x += pe.x; v.y += pe.y; v.z += pe.z; v.w += pe.w;
  *(float4*)(h + (size_t)bp * 768 + t * 4) = v;
}

// ---------------- row LayerNorm fp32 -> bf16 ------------------------------
__device__ __forceinline__ void ln_row(const float* xr, const float* w,
                                       const float* b, unsigned short* yr,
                                       float* red) {
  int t = threadIdx.x;  // 256
  float v0 = xr[t], v1 = xr[t + 256], v2 = xr[t + 512];
  float s = blockReduceSum256(v0 + v1 + v2, red);
  float mu = s * (1.f / 768.f);
  float d0 = v0 - mu, d1 = v1 - mu, d2 = v2 - mu;
  float q = blockReduceSum256(d0 * d0 + d1 * d1 + d2 * d2, red);
  float rstd = rsqrtf(q * (1.f / 768.f) + 1e-5f);
  yr[t]       = f2bf(d0 * rstd * w[t]       + b[t]);
  yr[t + 256] = f2bf(d1 * rstd * w[t + 256] + b[t + 256]);
  yr[t + 512] = f2bf(d2 * rstd * w[t + 512] + b[t + 512]);
}

__global__ void ln_kernel(const float* x, const float* w, const float* b,
                          unsigned short* y) {
  __shared__ float red[4];
  size_t r = blockIdx.x;
  ln_row(x + r * 768, w, b, y + r * 768, red);
}

// gather the (eot+V-1) token per (m,n) and apply final LN
__global__ void gather_ln_kernel(const float* h, const int* eot,
                                 const float* w, const float* b,
                                 unsigned short* y) {
  __shared__ float red[4];
  int r = blockIdx.x;               // 0..511 = m*64+n
  int n = r & 63;
  size_t row = (size_t)r * 77 + (eot[n] + 7);
  ln_row(h + row * 768, w, b, y + (size_t)r * 768, red);
}

// ---------------------------------------------------------------------------
// GEMM: C[rows,cols] = A_bf16[rows,K] @ W_bf16[cols,K]^T
// 256x256 tile, BK=64, 8 waves (2Mx4N), 8-phase counted-vmcnt schedule.
// MODE 0: +bias -> bf16    MODE 1: gelu(+bias) -> bf16
// MODE 2: h += (+bias), fp32 in/out    MODE 3: (+bias?) -> fp32
// Main-loop LDS layout / stage schedule: see round-4 comment (unchanged).
// Epilogue: per-wave private LDS transpose slab float[64][68], col XOR'd by
// (row&3)<<4; write 64 b32/half, read 16 b128/half, store 16 vec/half.
// ---------------------------------------------------------------------------
template <int MODE>
__global__ __launch_bounds__(512, 2)
void gemm256_kernel(const unsigned short* __restrict__ A,
                    const unsigned short* __restrict__ W,
                    const float* __restrict__ bias, void* __restrict__ outp,
                    const float* __restrict__ resid, int K, int cols) {
  __shared__ __align__(16) union LDSU {
    struct { unsigned short As[2][16384]; unsigned short Bs[2][16384]; } m;
    float ep[8][4352];   // 8 waves x (64 rows x 68 floats) = 136 KiB
  } u;

  const int gx = gridDim.x;
  const int G = gx * gridDim.y;
  const int P = blockIdx.y * gx + blockIdx.x;
  // bijective XCD swizzle (m204 form; handles G%8 != 0)
  const int q8 = G >> 3, r8 = G & 7;
  const int xcd = P & 7, ord = P >> 3;
  const int Lid =
      (xcd < r8 ? xcd * (q8 + 1) : r8 * (q8 + 1) + (xcd - r8) * q8) + ord;
  const int col0 = (Lid % gx) * 256;
  const int row0 = (Lid / gx) * 256;

  const int t = threadIdx.x;
  const int wave = t >> 6, lane = t & 63;
  const int m = lane & 15, quad = lane >> 4;
  const int wm = wave >> 2, wn = wave & 3;

  // ---- staging addresses: thread t stages 16B at LDS linear o=t*16 (+8KB
  // for round 1).  lr0 = LDS row within 64-row round; source column is the
  // XOR-swizzled chunk so a swizzled ds_read retrieves linear data.
  const int lr0 = t >> 3;                                    // 0..63
  const int cbe = ((t & 7) << 3) ^ ((lr0 & 7) << 3);         // elems in row
  const unsigned short* Abase = A + (size_t)(row0 + lr0) * K + cbe;
  const int grB0 = (lr0 & 31) + ((lr0 >> 5) << 6);
  const unsigned short* Bbase = W + (size_t)(col0 + grB0) * K + cbe;

#define STAGE_A(b, h, kb) {                                                  \
    const unsigned short* _p = Abase + (size_t)(h) * 64 * K + (kb);          \
    glds16(_p, &u.m.As[b][(h) * 8192 + wave * 512]);                         \
    glds16(_p + (size_t)128 * K, &u.m.As[b][(h) * 8192 + 4096 + wave * 512]); }
#define STAGE_B(b, h, kb) {                                                  \
    const unsigned short* _p = Bbase + (size_t)(h) * 32 * K + (kb);          \
    glds16(_p, &u.m.Bs[b][(h) * 8192 + wave * 512]);                         \
    glds16(_p + (size_t)128 * K, &u.m.Bs[b][(h) * 8192 + 4096 + wave * 512]); }

  // ---- fragment reads (swizzled): row = h*128 + waveRow + frag*16 + m
  const int aRow = wm * 64 + m;
  const int bRow = wn * 32 + m;
  const int sw = (m & 7) << 3;
  short8 af[4][2], bfr[2][2];
  floatx4 acc[8][4] = {};

#define RD_A(b, ha) {                                                        \
    _Pragma("unroll") for (int fi = 0; fi < 4; ++fi)                         \
    _Pragma("unroll") for (int ks = 0; ks < 2; ++ks)                         \
      af[fi][ks] = *(const short8*)&u.m.As[b][((ha) * 128 + aRow + fi * 16) * 64 \
                                          + (((ks << 5) | (quad << 3)) ^ sw)]; }
#define RD_B(b, hb) {                                                        \
    _Pragma("unroll") for (int fj = 0; fj < 2; ++fj)                         \
    _Pragma("unroll") for (int ks = 0; ks < 2; ++ks)                         \
      bfr[fj][ks] = *(const short8*)&u.m.Bs[b][((hb) * 128 + bRow + fj * 16) * 64\
                                          + (((ks << 5) | (quad << 3)) ^ sw)]; }
#define MFMA16(AH, BH) {                                                     \
    __builtin_amdgcn_s_setprio(1);                                           \
    _Pragma("unroll") for (int fi = 0; fi < 4; ++fi)                         \
    _Pragma("unroll") for (int fj = 0; fj < 2; ++fj)                         \
    _Pragma("unroll") for (int ks = 0; ks < 2; ++ks)                         \
      acc[(AH) * 4 + fi][(BH) * 2 + fj] =                                    \
          __builtin_amdgcn_mfma_f32_16x16x32_bf16(                           \
              af[fi][ks], bfr[fj][ks], acc[(AH) * 4 + fi][(BH) * 2 + fj],    \
              0, 0, 0);                                                      \
    __builtin_amdgcn_s_setprio(0); }
#define SBZ() __builtin_amdgcn_sched_barrier(0)
#define BAR() { SBZ(); __builtin_amdgcn_s_barrier(); SBZ(); }
#define WLDS() { asm volatile("s_waitcnt lgkmcnt(0)" ::: "memory"); SBZ(); }
#define WVM6() { asm volatile("s_waitcnt vmcnt(6)" ::: "memory"); SBZ(); }

  const int NT = K >> 6;        // 64-wide K tiles (12 or 48; always even)
  const int NI = NT >> 1;

  // prologue: tile0 complete (8 loads) + tile1 {A h0, B h1, A h1} (6 loads)
  STAGE_A(0, 0, 0); STAGE_A(0, 1, 0); STAGE_B(0, 0, 0); STAGE_B(0, 1, 0);
  STAGE_A(1, 0, 64); STAGE_B(1, 1, 64); STAGE_A(1, 1, 64);
  WVM6();            // tile0 landed; tile1's 6 loads may remain in flight
  BAR();

  for (int i = 0; i < NI; ++i) {
    const int T = i << 1;
    const int k1 = (T + 1) << 6;
    const int k2 = (T + 2 < NT ? T + 2 : NT - 1) << 6;
    const int k3 = (T + 3 < NT ? T + 3 : NT - 1) << 6;
    // ---- tile T (buf0), quadrant order (A0,B0)(A0,B1)(A1,B1)(A1,B0)
    // p1
    RD_A(0, 0); RD_B(0, 0); STAGE_B(1, 0, k1);
    BAR(); WLDS(); MFMA16(0, 0); BAR();
    // p2
    RD_B(0, 1); STAGE_A(0, 0, k2);
    BAR(); WLDS(); MFMA16(0, 1); BAR();
    // p3
    RD_A(0, 1); STAGE_B(0, 1, k2);
    BAR(); WLDS(); MFMA16(1, 1); BAR();
    // p4
    RD_B(0, 0); STAGE_A(0, 1, k2); WVM6();
    BAR(); WLDS(); MFMA16(1, 0); BAR();
    // ---- tile T+1 (buf1)
    // p5
    RD_A(1, 0); RD_B(1, 0); STAGE_B(0, 0, k2);
    BAR(); WLDS(); MFMA16(0, 0); BAR();
    // p6
    RD_B(1, 1); STAGE_A(1, 0, k3);
    BAR(); WLDS(); MFMA16(0, 1); BAR();
    // p7
    RD_A(1, 1); STAGE_B(1, 1, k3);
    BAR(); WLDS(); MFMA16(1, 1); BAR();
    // p8
    RD_B(1, 0); STAGE_A(1, 1, k3); WVM6();
    BAR(); WLDS(); MFMA16(1, 0); BAR();
  }
  // drain tail prefetches (they write into As/Bs which the epilogue reuses),
  // then barrier so no wave's slab gets trampled by another wave's glds.
  asm volatile("s_waitcnt vmcnt(0)" ::: "memory");
  BAR();

  // ---- epilogue: per-wave LDS transpose -> coalesced vector I/O ----------
  float* Ep = &u.ep[wave][0];
  const int g = lane >> 4, c4 = lane & 15;
  float bi[4];
  #pragma unroll
  for (int fj = 0; fj < 4; ++fj)
    bi[fj] = bias ? bias[col0 + wn * 64 + fj * 16 + m] : 0.f;

  #pragma unroll
  for (int h = 0; h < 2; ++h) {
    // scatter acc (+bias, +gelu) into the private slab; col XOR (row&3)<<4
    #pragma unroll
    for (int fi2 = 0; fi2 < 4; ++fi2) {
      #pragma unroll
      for (int fj = 0; fj < 4; ++fj) {
        #pragma unroll
        for (int reg = 0; reg < 4; ++reg) {
          float v = acc[h * 4 + fi2][fj][reg] + bi[fj];
          if (MODE == 1) v = v / (1.f + __expf(-1.702f * v));
          const int row_l = fi2 * 16 + quad * 4 + reg;   // row_l&3 == reg
          Ep[row_l * 68 + ((fj * 16 + m) ^ (reg << 4))] = v;
        }
      }
    }
    asm volatile("s_waitcnt lgkmcnt(0)" ::: "memory");
    SBZ();
    // gather 4-row quads; lanes cover 4 rows x 16 chunks -> coalesced
    #pragma unroll
    for (int tt = 0; tt < 16; ++tt) {
      const int row_l = tt * 4 + g;                      // row_l&3 == g
      const float4 vv =
          *(const float4*)&Ep[row_l * 68 + ((c4 * 4) ^ (g << 4))];
      const size_t grow = (size_t)(row0 + wm * 128 + h * 64 + row_l);
      const size_t idx = grow * cols + (col0 + wn * 64 + c4 * 4);
      if (MODE == 0 || MODE == 1) {
        ushort4v o;
        o.x = f2bf(vv.x); o.y = f2bf(vv.y);
        o.z = f2bf(vv.z); o.w = f2bf(vv.w);
        *(ushort4v*)((unsigned short*)outp + idx) = o;
      } else if (MODE == 2) {
        const float4 r = *(const float4*)(resid + idx);
        float4 ov;
        ov.x = vv.x + r.x; ov.y = vv.y + r.y;
        ov.z = vv.z + r.z; ov.w = vv.w + r.w;
        *(float4*)((float*)outp + idx) = ov;
      } else {
        *(float4*)((float*)outp + idx) = vv;
      }
    }
    // same-wave slab reuse across halves is safe: DS ops of a wave execute
    // in order, and read data is consumed before half-1 writes issue.
  }
#undef STAGE_A
#undef STAGE_B
#undef RD_A
#undef RD_B
#undef MFMA16
#undef SBZ
#undef BAR
#undef WLDS
#undef WVM6
}

// ---------------- fused attention per (batch, head) -----------------------
// QK^T via MFMA (lower-triangular tiles only), fp32 softmax, P@V via MFMA.
__global__ __launch_bounds__(256)
void attn_kernel(const unsigned short* qkv, unsigned short* o) {
  __shared__ __align__(16) union U {
    struct { unsigned short Qs[80 * 64]; unsigned short Ks[80 * 64]; } qk;
    unsigned short Ps[80 * 96];
  } u;
  __shared__ __align__(16) unsigned short Vt[64 * 96];
  __shared__ float S[80 * 81];     // stride 81: bank-conflict-free rows

  int b = blockIdx.x, hh = blockIdx.y;
  int t = threadIdx.x, wave = t >> 6, lane = t & 63;
  int m = lane & 15, quad = lane >> 4;
  const unsigned short* base = qkv + (size_t)b * 77 * 2304 + hh * 64;

  // stage Q,K rows (pad rows 77..79 with zeros)
  for (int c = t; c < 640; c += 256) {
    int l = c >> 3, kc = (c & 7) * 8;
    uint4v q = {0, 0, 0, 0}, k = {0, 0, 0, 0};
    if (l < 77) {
      q = *(const uint4v*)(base + (size_t)l * 2304 + kc);
      k = *(const uint4v*)(base + (size_t)l * 2304 + 768 + kc);
    }
    *(uint4v*)(u.qk.Qs + l * 64 + kc) = q;
    *(uint4v*)(u.qk.Ks + l * 64 + kc) = k;
  }
  // stage V transposed: Vt[d][l], l padded to 96
  for (int c = t; c < 768; c += 256) {
    int l = c >> 3, d0 = (c & 7) * 8;
    union { uint4v v; unsigned short s[8]; } vv;
    vv.v = (uint4v){0, 0, 0, 0};
    if (l < 77) vv.v = *(const uint4v*)(base + (size_t)l * 2304 + 1536 + d0);
    #pragma unroll
    for (int j = 0; j < 8; j++) Vt[(d0 + j) * 96 + l] = vv.s[j];
  }
  __syncthreads();

  // S = Q K^T : lower-triangular 16x16 tiles (15 of 25)
  for (int idx = wave; idx < 15; idx += 4) {
    int ti = 0, a2 = 0;
    while (a2 + ti + 1 <= idx) { a2 += ti + 1; ti++; }
    int tj = idx - a2;
    floatx4 sa = {};
    #pragma unroll
    for (int k0 = 0; k0 < 64; k0 += 32) {
      short8 aq = *(const short8*)(u.qk.Qs + (ti * 16 + m) * 64 + k0 + quad * 8);
      short8 bk = *(const short8*)(u.qk.Ks + (tj * 16 + m) * 64 + k0 + quad * 8);
      sa = __builtin_amdgcn_mfma_f32_16x16x32_bf16(aq, bk, sa, 0, 0, 0);
    }
    #pragma unroll
    for (int r = 0; r < 4; r++)
      S[(ti * 16 + quad * 4 + r) * 81 + tj * 16 + m] = sa[r];
  }
  __syncthreads();

  // causal softmax row-per-thread (scale 1/8), write P bf16 (96-padded)
  if (t < 80) {
    int r = t;
    if (r < 77) {
      float mx = -1e30f;
      for (int j = 0; j <= r; j++) mx = fmaxf(mx, S[r * 81 + j]);
      float sum = 0.f;
      for (int j = 0; j <= r; j++) {
        float e = __expf((S[r * 81 + j] - mx) * 0.125f);
        S[r * 81 + j] = e; sum += e;
      }
      float inv = 1.f / sum;
      for (int j = 0; j < 96; j++)
        u.Ps[r * 96 + j] = (j <= r) ? f2bf(S[r * 81 + j] * inv) : (unsigned short)0;
    } else {
      for (int j = 0; j < 96; j++) u.Ps[r * 96 + j] = 0;
    }
  }
  __syncthreads();

  // O = P @ V : 5x4 tiles, K padded to 96
  for (int idx = wave; idx < 20; idx += 4) {
    int ti = idx >> 2, tj = idx & 3;
    floatx4 oa = {};
    #pragma unroll
    for (int k0 = 0; k0 < 96; k0 += 32) {
      short8 ap = *(const short8*)(u.Ps + (ti * 16 + m) * 96 + k0 + quad * 8);
      short8 bv = *(const short8*)(Vt + (tj * 16 + m) * 96 + k0 + quad * 8);
      oa = __builtin_amdgcn_mfma_f32_16x16x32_bf16(ap, bv, oa, 0, 0, 0);
    }
    #pragma unroll
    for (int r = 0; r < 4; r++) {
      int l = ti * 16 + quad * 4 + r;
      if (l < 77)
        o[((size_t)b * 77 + l) * 768 + hh * 64 + tj * 16 + m] = f2bf(oa[r]);
    }
  }
}

// ---------------- final: per-row normalize, mean over n, renormalize ------
__global__ void reduce_kernel(const float* feats, float* out) {
  __shared__ float red[4];
  int mfig = blockIdx.x;   // 0..7
  int t = threadIdx.x;     // 256
  float a0 = 0.f, a1 = 0.f, a2 = 0.f;
  for (int n = 0; n < 64; n++) {
    const float* fr = feats + ((size_t)mfig * 64 + n) * 768;
    float v0 = fr[t], v1 = fr[t + 256], v2 = fr[t + 512];
    float q = blockReduceSum256(v0 * v0 + v1 * v1 + v2 * v2, red);
    float rn = rsqrtf(q);
    a0 += v0 * rn; a1 += v1 * rn; a2 += v2 * rn;
  }
  float q = blockReduceSum256(a0 * a0 + a1 * a1 + a2 * a2, red);
  float rn = rsqrtf(q);
  out[mfig * 768 + t]       = a0 * rn;
  out[mfig * 768 + t + 256] = a1 * rn;
  out[mfig * 768 + t + 512] = a2 * rn;
}

// ---------------------------------------------------------------------------
extern "C" void kernel_launch(void* const* d_in, const int* in_sizes, int n_in,
                              void* d_out, int out_size, void* d_ws,
                              size_t ws_size, hipStream_t stream) {
  (void)in_sizes; (void)n_in; (void)out_size; (void)ws_size;
  const int*   text      = (const int*)d_in[0];
  const float* visf      = (const float*)d_in[1];
  const float* tok_emb   = (const float*)d_in[2];
  const float* pos_emb   = (const float*)d_in[3];
  const float* ln1_w     = (const float*)d_in[4];
  const float* ln1_b     = (const float*)d_in[5];
  const float* in_w      = (const float*)d_in[6];
  const float* in_b      = (const float*)d_in[7];
  const float* out_w     = (const float*)d_in[8];
  const float* out_b     = (const float*)d_in[9];
  const float* ln2_w     = (const float*)d_in[10];
  const float* ln2_b     = (const float*)d_in[11];
  const float* fc_w      = (const float*)d_in[12];
  const float* fc_b      = (const float*)d_in[13];
  const float* pj_w      = (const float*)d_in[14];
  const float* pj_b      = (const float*)d_in[15];
  const float* lnf_w     = (const float*)d_in[16];
  const float* lnf_b     = (const float*)d_in[17];
  const float* text_proj = (const float*)d_in[18];
  float* out = (float*)d_out;

  char* p = (char*)d_ws;
  auto alloc = [&](size_t bytes) {
    char* q = p; p += (bytes + 255) & ~(size_t)255; return q;
  };
  int* posy = (int*)alloc(64 * 4);
  int* eot  = (int*)alloc(64 * 4);
  float* h            = (float*)alloc((size_t)ROWS * 768 * 4);          // 121 MB
  unsigned short* y   = (unsigned short*)alloc((size_t)ROWS * 768 * 2); // 61 MB
  unsigned short* qkv = (unsigned short*)alloc((size_t)ROWS * 2304 * 2);// 182 MB
  unsigned short* ob  = (unsigned short*)alloc((size_t)ROWS * 768 * 2); // 61 MB
  unsigned short* act = qkv;  // aliases qkv+ob (dead when act is live)
  // per-layer bf16 weight buffer (reused each layer; stream-ordered)
  unsigned short* wqkv = (unsigned short*)alloc((size_t)2304 * 768 * 2);
  unsigned short* wout = (unsigned short*)alloc((size_t)768 * 768 * 2);
  unsigned short* wfc  = (unsigned short*)alloc((size_t)3072 * 768 * 2);
  unsigned short* wpj  = (unsigned short*)alloc((size_t)768 * 3072 * 2);
  unsigned short* wt   = (unsigned short*)alloc((size_t)768 * 768 * 2);
  unsigned short* afin = (unsigned short*)alloc((size_t)512 * 768 * 2);
  float* feats = (float*)alloc((size_t)512 * 768 * 4);

  idx_kernel<<<1, 64, 0, stream>>>(text, posy, eot);
  transT_kernel<<<(768 * 768) / 256, 256, 0, stream>>>(text_proj, wt);
  embed_kernel<<<ROWS, 192, 0, stream>>>(text, visf, tok_emb, pos_emb, posy, h);

  const int NQKV = 2304 * 768, NOUT = 768 * 768, NFC = 3072 * 768;
  for (int l = 0; l < 12; l++) {
    cvt_kernel<<<NQKV / 1024, 256, 0, stream>>>(in_w + (size_t)l * NQKV, wqkv, NQKV);
    cvt_kernel<<<NOUT / 1024, 256, 0, stream>>>(out_w + (size_t)l * NOUT, wout, NOUT);
    cvt_kernel<<<NFC / 1024, 256, 0, stream>>>(fc_w + (size_t)l * NFC, wfc, NFC);
    cvt_kernel<<<NFC / 1024, 256, 0, stream>>>(pj_w + (size_t)l * NFC, wpj, NFC);

    ln_kernel<<<ROWS, 256, 0, stream>>>(h, ln1_w + l * 768, ln1_b + l * 768, y);
    gemm256_kernel<0><<<dim3(9, 154), 512, 0, stream>>>(
        y, wqkv, in_b + l * 2304, qkv, nullptr, 768, 2304);
    attn_kernel<<<dim3(512, 12), 256, 0, stream>>>(qkv, ob);
    gemm256_kernel<2><<<dim3(3, 154), 512, 0, stream>>>(
        ob, wout, out_b + l * 768, h, h, 768, 768);
    ln_kernel<<<ROWS, 256, 0, stream>>>(h, ln2_w + l * 768, ln2_b + l * 768, y);
    gemm256_kernel<1><<<dim3(12, 154), 512, 0, stream>>>(
        y, wfc, fc_b + l * 3072, act, nullptr, 768, 3072);
    gemm256_kernel<2><<<dim3(3, 154), 512, 0, stream>>>(
        act, wpj, pj_b + l * 768, h, h, 3072, 768);
  }

  gather_ln_kernel<<<512, 256, 0, stream>>>(h, eot, lnf_w, lnf_b, afin);
  gemm256_kernel<3><<<dim3(3, 2), 512, 0, stream>>>(
      afin, wt, nullptr, feats, nullptr, 768, 768);
  reduce_kernel<<<8, 256, 0, stream>>>(feats, out);
}

// Round 3
// 11627.848 us; speedup vs baseline: 1.2630x; 1.0578x over previous
//
#include <hip/hip_runtime.h>

// ---------------------------------------------------------------------------
// CLIP text transformer forward, MI355X/gfx950.
// Shapes: N=64, L=77, D=768, V=8, M=8, H=12 heads (hd=64), 12 layers.
// Rows = M*N*L = 39424 = 154*256 (exact 256-row tiles).
// Round 6: main loop = 256x256 8-phase pipelined template (unchanged).
//  - peeled final iteration: no clamped garbage prefetches, exact vmcnt(0)
//    at p4, no post-loop drain (p8 barrier protects LDS reuse)
//  - epilogue math: GELU via raw v_rcp, bf16 via packed v_cvt_pk_bf16_f32
//  - LayerNorm: wave-per-row (shfl_xor reduce, no syncthreads), vectorized
//  - weight cvt: 4 dispatches/layer -> 1, packed bf16 stores
// ---------------------------------------------------------------------------

typedef short short8 __attribute__((ext_vector_type(8)));
typedef float floatx4 __attribute__((ext_vector_type(4)));
typedef unsigned int uint4v __attribute__((ext_vector_type(4)));
typedef unsigned short ushort4v __attribute__((ext_vector_type(4)));

#define SOV_TOK 49408
#define EOT_TOK 49407
#define ROWS 39424      // 512*77

__device__ __forceinline__ unsigned short f2bf(float f) {
  union { float f; unsigned int u; } v; v.f = f;
  return (unsigned short)((v.u + 0x7fffu + ((v.u >> 16) & 1u)) >> 16);
}

// packed round-nearest-even f32x2 -> bf16x2 (low = a, high = b)
__device__ __forceinline__ unsigned int pk_bf16(float a, float b) {
  unsigned int r;
  asm("v_cvt_pk_bf16_f32 %0, %1, %2" : "=v"(r) : "v"(a), "v"(b));
  return r;
}

typedef const __attribute__((address_space(1))) void* gptr_t;
typedef __attribute__((address_space(3))) void* lptr_t;
__device__ __forceinline__ void glds16(const void* g, void* l) {
  __builtin_amdgcn_global_load_lds((gptr_t)g, (lptr_t)l, 16, 0, 0);
}

__device__ __forceinline__ float blockReduceSum256(float v, float* red) {
  __syncthreads();                    // protect red reuse across calls
  #pragma unroll
  for (int off = 32; off; off >>= 1) v += __shfl_down(v, off, 64);
  int wave = threadIdx.x >> 6, lane = threadIdx.x & 63;
  if (lane == 0) red[wave] = v;
  __syncthreads();
  return red[0] + red[1] + red[2] + red[3];
}

// ---------------- index scan: first SOV / first EOT per sequence ----------
__global__ void idx_kernel(const int* text, int* posy, int* eot) {
  int n = threadIdx.x;  // 64 threads
  int py = 0, et = 0; bool fp = false, fe = false;
  for (int j = 0; j < 77; j++) {
    int v = text[n * 77 + j];
    if (!fp && v == SOV_TOK) { py = j; fp = true; }
    if (!fe && v == EOT_TOK) { et = j; fe = true; }
  }
  posy[n] = py; eot[n] = et;
}

// ---------------- fused fp32 -> bf16 conversion of 4 weight mats ----------
// sizes: NQKV=2304*768, NOUT=768*768, NFC=3072*768 (x2). All /4 exact.
__global__ __launch_bounds__(256)
void cvt4_kernel(const float* __restrict__ w0, const float* __restrict__ w1,
                 const float* __restrict__ w2, const float* __restrict__ w3,
                 unsigned short* __restrict__ d0, unsigned short* __restrict__ d1,
                 unsigned short* __restrict__ d2, unsigned short* __restrict__ d3) {
  const int NQKV = 2304 * 768, NOUT = 768 * 768, NFC = 3072 * 768;
  int i = (blockIdx.x * 256 + threadIdx.x) * 4;
  const float* s; unsigned short* d;
  if (i < NQKV)                    { s = w0 + i;  d = d0 + i; }
  else if (i < NQKV + NOUT)        { int j = i - NQKV; s = w1 + j; d = d1 + j; }
  else if (i < NQKV + NOUT + NFC)  { int j = i - NQKV - NOUT; s = w2 + j; d = d2 + j; }
  else                             { int j = i - NQKV - NOUT - NFC; s = w3 + j; d = d3 + j; }
  float4 v = *(const float4*)s;
  uint2 o; o.x = pk_bf16(v.x, v.y); o.y = pk_bf16(v.z, v.w);
  *(uint2*)d = o;
}

// transpose text_proj (D,E) -> bf16 (E,D)
__global__ void transT_kernel(const float* tp, unsigned short* wt) {
  int id = blockIdx.x * 256 + threadIdx.x;   // 768*768 total
  int d = id / 768, e = id % 768;
  wt[(size_t)e * 768 + d] = f2bf(tp[id]);
}

// ---------------- build h = splice(tok_emb, visual) + pos_emb -------------
__global__ void embed_kernel(const int* text, const float* vis,
                             const float* tok_emb, const float* pos_emb,
                             const int* posy, float* h) {
  int bp = blockIdx.x;              // 0..39423 = b*77+p
  int b = bp / 77, p = bp % 77;
  int mm = b >> 6, n = b & 63;
  int py = posy[n];
  int t = threadIdx.x;              // 192 threads * float4 = 768
  const float* srcp;
  if (p >= py && p < py + 8) {
    srcp = vis + ((size_t)mm * 8 + (p - py)) * 768;
  } else {
    int src = (p < py) ? p : p - 7;
    src = src < 0 ? 0 : (src > 76 ? 76 : src);
    int tok = text[n * 77 + src];
    srcp = tok_emb + (size_t)tok * 768;
  }
  float4 v = *(const float4*)(srcp + t * 4);
  float4 pe = *(const float4*)(pos_emb + (size_t)p * 768 + t * 4);
  v.x += pe.x; v.y += pe.y; v.z += pe.z; v.w += pe.w;
  *(float4*)(h + (size_t)bp * 768 + t * 4) = v;
}

// ---------------- wave-per-row LayerNorm fp32 -> bf16 ---------------------
// 4 rows per 256-thread block; each wave owns one row (12 f32/lane).
__global__ __launch_bounds__(256)
void ln4_kernel(const float* __restrict__ x, const float* __restrict__ w,
                const float* __restrict__ b, unsigned short* __restrict__ y) {
  const int wave = threadIdx.x >> 6, lane = threadIdx.x & 63;
  const size_t r = (size_t)blockIdx.x * 4 + wave;
  const float* xr = x + r * 768;
  const int c = lane * 4;
  const float4 v0 = *(const float4*)(xr + c);
  const float4 v1 = *(const float4*)(xr + 256 + c);
  const float4 v2 = *(const float4*)(xr + 512 + c);
  float s = v0.x + v0.y + v0.z + v0.w + v1.x + v1.y + v1.z + v1.w +
            v2.x + v2.y + v2.z + v2.w;
  #pragma unroll
  for (int off = 32; off; off >>= 1) s += __shfl_xor(s, off, 64);
  const float mu = s * (1.f / 768.f);
  const float d0 = v0.x - mu, d1 = v0.y - mu, d2 = v0.z - mu, d3 = v0.w - mu;
  const float d4 = v1.x - mu, d5 = v1.y - mu, d6 = v1.z - mu, d7 = v1.w - mu;
  const float d8 = v2.x - mu, d9 = v2.y - mu, d10 = v2.z - mu, d11 = v2.w - mu;
  float q = d0 * d0 + d1 * d1 + d2 * d2 + d3 * d3 + d4 * d4 + d5 * d5 +
            d6 * d6 + d7 * d7 + d8 * d8 + d9 * d9 + d10 * d10 + d11 * d11;
  #pragma unroll
  for (int off = 32; off; off >>= 1) q += __shfl_xor(q, off, 64);
  const float rstd = rsqrtf(q * (1.f / 768.f) + 1e-5f);
  const float4 w0 = *(const float4*)(w + c);
  const float4 w1 = *(const float4*)(w + 256 + c);
  const float4 w2 = *(const float4*)(w + 512 + c);
  const float4 b0 = *(const float4*)(b + c);
  const float4 b1 = *(const float4*)(b + 256 + c);
  const float4 b2 = *(const float4*)(b + 512 + c);
  unsigned short* yr = y + r * 768;
  uint2 o;
  o.x = pk_bf16(d0 * rstd * w0.x + b0.x, d1 * rstd * w0.y + b0.y);
  o.y = pk_bf16(d2 * rstd * w0.z + b0.z, d3 * rstd * w0.w + b0.w);
  *(uint2*)(yr + c) = o;
  o.x = pk_bf16(d4 * rstd * w1.x + b1.x, d5 * rstd * w1.y + b1.y);
  o.y = pk_bf16(d6 * rstd * w1.z + b1.z, d7 * rstd * w1.w + b1.w);
  *(uint2*)(yr + 256 + c) = o;
  o.x = pk_bf16(d8 * rstd * w2.x + b2.x, d9 * rstd * w2.y + b2.y);
  o.y = pk_bf16(d10 * rstd * w2.z + b2.z, d11 * rstd * w2.w + b2.w);
  *(uint2*)(yr + 512 + c) = o;
}

// gather the (eot+V-1) token per (m,n) and apply final LN
__global__ void gather_ln_kernel(const float* h, const int* eot,
                                 const float* w, const float* b,
                                 unsigned short* y) {
  __shared__ float red[4];
  int r = blockIdx.x;               // 0..511 = m*64+n
  int n = r & 63;
  size_t row = (size_t)r * 77 + (eot[n] + 7);
  const float* xr = h + row * 768;
  int t = threadIdx.x;  // 256
  float v0 = xr[t], v1 = xr[t + 256], v2 = xr[t + 512];
  float s = blockReduceSum256(v0 + v1 + v2, red);
  float mu = s * (1.f / 768.f);
  float e0 = v0 - mu, e1 = v1 - mu, e2 = v2 - mu;
  float q = blockReduceSum256(e0 * e0 + e1 * e1 + e2 * e2, red);
  float rstd = rsqrtf(q * (1.f / 768.f) + 1e-5f);
  unsigned short* yr = y + (size_t)r * 768;
  yr[t]       = f2bf(e0 * rstd * w[t]       + b[t]);
  yr[t + 256] = f2bf(e1 * rstd * w[t + 256] + b[t + 256]);
  yr[t + 512] = f2bf(e2 * rstd * w[t + 512] + b[t + 512]);
}

// ---------------------------------------------------------------------------
// GEMM: C[rows,cols] = A_bf16[rows,K] @ W_bf16[cols,K]^T
// 256x256 tile, BK=64, 8 waves (2Mx4N), 8-phase counted-vmcnt schedule.
// MODE 0: +bias -> bf16    MODE 1: gelu(+bias) -> bf16
// MODE 2: h += (+bias), fp32 in/out    MODE 3: (+bias?) -> fp32
// Main-loop LDS layout / stage schedule: see round-4 comment (unchanged).
// Final iteration peeled: only the single still-real stage (B1h0 of tile
// NT-1) is issued; p4 waits vmcnt(0) exactly; nothing outstanding after.
// Epilogue: per-wave private LDS transpose slab float[64][68], col XOR'd by
// (row&3)<<4; GELU via raw v_rcp; bf16 stores via v_cvt_pk_bf16_f32.
// ---------------------------------------------------------------------------
template <int MODE>
__global__ __launch_bounds__(512, 2)
void gemm256_kernel(const unsigned short* __restrict__ A,
                    const unsigned short* __restrict__ W,
                    const float* __restrict__ bias, void* __restrict__ outp,
                    const float* __restrict__ resid, int K, int cols) {
  __shared__ __align__(16) union LDSU {
    struct { unsigned short As[2][16384]; unsigned short Bs[2][16384]; } m;
    float ep[8][4352];   // 8 waves x (64 rows x 68 floats) = 136 KiB
  } u;

  const int gx = gridDim.x;
  const int G = gx * gridDim.y;
  const int P = blockIdx.y * gx + blockIdx.x;
  // bijective XCD swizzle (m204 form; handles G%8 != 0)
  const int q8 = G >> 3, r8 = G & 7;
  const int xcd = P & 7, ord = P >> 3;
  const int Lid =
      (xcd < r8 ? xcd * (q8 + 1) : r8 * (q8 + 1) + (xcd - r8) * q8) + ord;
  const int col0 = (Lid % gx) * 256;
  const int row0 = (Lid / gx) * 256;

  const int t = threadIdx.x;
  const int wave = t >> 6, lane = t & 63;
  const int m = lane & 15, quad = lane >> 4;
  const int wm = wave >> 2, wn = wave & 3;

  // ---- staging addresses: thread t stages 16B at LDS linear o=t*16 (+8KB
  // for round 1).  lr0 = LDS row within 64-row round; source column is the
  // XOR-swizzled chunk so a swizzled ds_read retrieves linear data.
  const int lr0 = t >> 3;                                    // 0..63
  const int cbe = ((t & 7) << 3) ^ ((lr0 & 7) << 3);         // elems in row
  const unsigned short* Abase = A + (size_t)(row0 + lr0) * K + cbe;
  const int grB0 = (lr0 & 31) + ((lr0 >> 5) << 6);
  const unsigned short* Bbase = W + (size_t)(col0 + grB0) * K + cbe;

#define STAGE_A(b, h, kb) {                                                  \
    const unsigned short* _p = Abase + (size_t)(h) * 64 * K + (kb);          \
    glds16(_p, &u.m.As[b][(h) * 8192 + wave * 512]);                         \
    glds16(_p + (size_t)128 * K, &u.m.As[b][(h) * 8192 + 4096 + wave * 512]); }
#define STAGE_B(b, h, kb) {                                                  \
    const unsigned short* _p = Bbase + (size_t)(h) * 32 * K + (kb);          \
    glds16(_p, &u.m.Bs[b][(h) * 8192 + wave * 512]);                         \
    glds16(_p + (size_t)128 * K, &u.m.Bs[b][(h) * 8192 + 4096 + wave * 512]); }

  // ---- fragment reads (swizzled): row = h*128 + waveRow + frag*16 + m
  const int aRow = wm * 64 + m;
  const int bRow = wn * 32 + m;
  const int sw = (m & 7) << 3;
  short8 af[4][2], bfr[2][2];
  floatx4 acc[8][4] = {};

#define RD_A(b, ha) {                                                        \
    _Pragma("unroll") for (int fi = 0; fi < 4; ++fi)                         \
    _Pragma("unroll") for (int ks = 0; ks < 2; ++ks)                         \
      af[fi][ks] = *(const short8*)&u.m.As[b][((ha) * 128 + aRow + fi * 16) * 64 \
                                          + (((ks << 5) | (quad << 3)) ^ sw)]; }
#define RD_B(b, hb) {                                                        \
    _Pragma("unroll") for (int fj = 0; fj < 2; ++fj)                         \
    _Pragma("unroll") for (int ks = 0; ks < 2; ++ks)                         \
      bfr[fj][ks] = *(const short8*)&u.m.Bs[b][((hb) * 128 + bRow + fj * 16) * 64\
                                          + (((ks << 5) | (quad << 3)) ^ sw)]; }
#define MFMA16(AH, BH) {                                                     \
    __builtin_amdgcn_s_setprio(1);                                           \
    _Pragma("unroll") for (int fi = 0; fi < 4; ++fi)                         \
    _Pragma("unroll") for (int fj = 0; fj < 2; ++fj)                         \
    _Pragma("unroll") for (int ks = 0; ks < 2; ++ks)                         \
      acc[(AH) * 4 + fi][(BH) * 2 + fj] =                                    \
          __builtin_amdgcn_mfma_f32_16x16x32_bf16(                           \
              af[fi][ks], bfr[fj][ks], acc[(AH) * 4 + fi][(BH) * 2 + fj],    \
              0, 0, 0);                                                      \
    __builtin_amdgcn_s_setprio(0); }
#define SBZ() __builtin_amdgcn_sched_barrier(0)
#define BAR() { SBZ(); __builtin_amdgcn_s_barrier(); SBZ(); }
#define WLDS() { asm volatile("s_waitcnt lgkmcnt(0)" ::: "memory"); SBZ(); }
#define WVM6() { asm volatile("s_waitcnt vmcnt(6)" ::: "memory"); SBZ(); }
#define WVM0() { asm volatile("s_waitcnt vmcnt(0)" ::: "memory"); SBZ(); }

  const int NT = K >> 6;        // 64-wide K tiles (12 or 48; always even)
  const int NI = NT >> 1;

  // prologue: tile0 complete (8 loads) + tile1 {A h0, B h1, A h1} (6 loads)
  STAGE_A(0, 0, 0); STAGE_A(0, 1, 0); STAGE_B(0, 0, 0); STAGE_B(0, 1, 0);
  STAGE_A(1, 0, 64); STAGE_B(1, 1, 64); STAGE_A(1, 1, 64);
  WVM6();            // tile0 landed; tile1's 6 loads may remain in flight
  BAR();

  for (int i = 0; i < NI - 1; ++i) {
    const int T = i << 1;
    const int k1 = (T + 1) << 6;
    const int k2 = (T + 2) << 6;
    const int k3 = (T + 3) << 6;
    // ---- tile T (buf0), quadrant order (A0,B0)(A0,B1)(A1,B1)(A1,B0)
    // p1
    RD_A(0, 0); RD_B(0, 0); STAGE_B(1, 0, k1);
    BAR(); WLDS(); MFMA16(0, 0); BAR();
    // p2
    RD_B(0, 1); STAGE_A(0, 0, k2);
    BAR(); WLDS(); MFMA16(0, 1); BAR();
    // p3
    RD_A(0, 1); STAGE_B(0, 1, k2);
    BAR(); WLDS(); MFMA16(1, 1); BAR();
    // p4
    RD_B(0, 0); STAGE_A(0, 1, k2); WVM6();
    BAR(); WLDS(); MFMA16(1, 0); BAR();
    // ---- tile T+1 (buf1)
    // p5
    RD_A(1, 0); RD_B(1, 0); STAGE_B(0, 0, k2);
    BAR(); WLDS(); MFMA16(0, 0); BAR();
    // p6
    RD_B(1, 1); STAGE_A(1, 0, k3);
    BAR(); WLDS(); MFMA16(0, 1); BAR();
    // p7
    RD_A(1, 1); STAGE_B(1, 1, k3);
    BAR(); WLDS(); MFMA16(1, 1); BAR();
    // p8
    RD_B(1, 0); STAGE_A(1, 1, k3); WVM6();
    BAR(); WLDS(); MFMA16(1, 0); BAR();
  }
  // ---- peeled final iteration (tiles NT-2 / NT-1): one real stage left
  {
    const int k1 = (NT - 1) << 6;
    // p1
    RD_A(0, 0); RD_B(0, 0); STAGE_B(1, 0, k1);
    BAR(); WLDS(); MFMA16(0, 0); BAR();
    // p2
    RD_B(0, 1);
    BAR(); WLDS(); MFMA16(0, 1); BAR();
    // p3
    RD_A(0, 1);
    BAR(); WLDS(); MFMA16(1, 1); BAR();
    // p4 — exact drain: all 8 outstanding loads are buf1 tile NT-1
    RD_B(0, 0); WVM0();
    BAR(); WLDS(); MFMA16(1, 0); BAR();
    // p5
    RD_A(1, 0); RD_B(1, 0);
    BAR(); WLDS(); MFMA16(0, 0); BAR();
    // p6
    RD_B(1, 1);
    BAR(); WLDS(); MFMA16(0, 1); BAR();
    // p7
    RD_A(1, 1);
    BAR(); WLDS(); MFMA16(1, 1); BAR();
    // p8 — closing BAR doubles as the epilogue LDS-reuse fence
    RD_B(1, 0);
    BAR(); WLDS(); MFMA16(1, 0); BAR();
  }

  // ---- epilogue: per-wave LDS transpose -> coalesced vector I/O ----------
  float* Ep = &u.ep[wave][0];
  const int g = lane >> 4, c4 = lane & 15;
  float bi[4];
  #pragma unroll
  for (int fj = 0; fj < 4; ++fj)
    bi[fj] = bias ? bias[col0 + wn * 64 + fj * 16 + m] : 0.f;

  #pragma unroll
  for (int h = 0; h < 2; ++h) {
    // scatter acc (+bias, +gelu) into the private slab; col XOR (row&3)<<4
    #pragma unroll
    for (int fi2 = 0; fi2 < 4; ++fi2) {
      #pragma unroll
      for (int fj = 0; fj < 4; ++fj) {
        #pragma unroll
        for (int reg = 0; reg < 4; ++reg) {
          float v = acc[h * 4 + fi2][fj][reg] + bi[fj];
          if (MODE == 1)
            v = v * __builtin_amdgcn_rcpf(1.f + __expf(-1.702f * v));
          const int row_l = fi2 * 16 + quad * 4 + reg;   // row_l&3 == reg
          Ep[row_l * 68 + ((fj * 16 + m) ^ (reg << 4))] = v;
        }
      }
    }
    asm volatile("s_waitcnt lgkmcnt(0)" ::: "memory");
    SBZ();
    // gather 4-row quads; lanes cover 4 rows x 16 chunks -> coalesced
    #pragma unroll
    for (int tt = 0; tt < 16; ++tt) {
      const int row_l = tt * 4 + g;                      // row_l&3 == g
      const float4 vv =
          *(const float4*)&Ep[row_l * 68 + ((c4 * 4) ^ (g << 4))];
      const size_t grow = (size_t)(row0 + wm * 128 + h * 64 + row_l);
      const size_t idx = grow * cols + (col0 + wn * 64 + c4 * 4);
      if (MODE == 0 || MODE == 1) {
        uint2 o;
        o.x = pk_bf16(vv.x, vv.y);
        o.y = pk_bf16(vv.z, vv.w);
        *(uint2*)((unsigned short*)outp + idx) = o;
      } else if (MODE == 2) {
        const float4 r = *(const float4*)(resid + idx);
        float4 ov;
        ov.x = vv.x + r.x; ov.y = vv.y + r.y;
        ov.z = vv.z + r.z; ov.w = vv.w + r.w;
        *(float4*)((float*)outp + idx) = ov;
      } else {
        *(float4*)((float*)outp + idx) = vv;
      }
    }
    // same-wave slab reuse across halves is safe: DS ops of a wave execute
    // in order, and read data is consumed before half-1 writes issue.
  }
#undef STAGE_A
#undef STAGE_B
#undef RD_A
#undef RD_B
#undef MFMA16
#undef SBZ
#undef BAR
#undef WLDS
#undef WVM6
#undef WVM0
}

// ---------------- fused attention per (batch, head) -----------------------
// QK^T via MFMA (lower-triangular tiles only), fp32 softmax, P@V via MFMA.
__global__ __launch_bounds__(256)
void attn_kernel(const unsigned short* qkv, unsigned short* o) {
  __shared__ __align__(16) union U {
    struct { unsigned short Qs[80 * 64]; unsigned short Ks[80 * 64]; } qk;
    unsigned short Ps[80 * 96];
  } u;
  __shared__ __align__(16) unsigned short Vt[64 * 96];
  __shared__ float S[80 * 81];     // stride 81: bank-conflict-free rows

  int b = blockIdx.x, hh = blockIdx.y;
  int t = threadIdx.x, wave = t >> 6, lane = t & 63;
  int m = lane & 15, quad = lane >> 4;
  const unsigned short* base = qkv + (size_t)b * 77 * 2304 + hh * 64;

  // stage Q,K rows (pad rows 77..79 with zeros)
  for (int c = t; c < 640; c += 256) {
    int l = c >> 3, kc = (c & 7) * 8;
    uint4v q = {0, 0, 0, 0}, k = {0, 0, 0, 0};
    if (l < 77) {
      q = *(const uint4v*)(base + (size_t)l * 2304 + kc);
      k = *(const uint4v*)(base + (size_t)l * 2304 + 768 + kc);
    }
    *(uint4v*)(u.qk.Qs + l * 64 + kc) = q;
    *(uint4v*)(u.qk.Ks + l * 64 + kc) = k;
  }
  // stage V transposed: Vt[d][l], l padded to 96
  for (int c = t; c < 768; c += 256) {
    int l = c >> 3, d0 = (c & 7) * 8;
    union { uint4v v; unsigned short s[8]; } vv;
    vv.v = (uint4v){0, 0, 0, 0};
    if (l < 77) vv.v = *(const uint4v*)(base + (size_t)l * 2304 + 1536 + d0);
    #pragma unroll
    for (int j = 0; j < 8; j++) Vt[(d0 + j) * 96 + l] = vv.s[j];
  }
  __syncthreads();

  // S = Q K^T : lower-triangular 16x16 tiles (15 of 25)
  for (int idx = wave; idx < 15; idx += 4) {
    int ti = 0, a2 = 0;
    while (a2 + ti + 1 <= idx) { a2 += ti + 1; ti++; }
    int tj = idx - a2;
    floatx4 sa = {};
    #pragma unroll
    for (int k0 = 0; k0 < 64; k0 += 32) {
      short8 aq = *(const short8*)(u.qk.Qs + (ti * 16 + m) * 64 + k0 + quad * 8);
      short8 bk = *(const short8*)(u.qk.Ks + (tj * 16 + m) * 64 + k0 + quad * 8);
      sa = __builtin_amdgcn_mfma_f32_16x16x32_bf16(aq, bk, sa, 0, 0, 0);
    }
    #pragma unroll
    for (int r = 0; r < 4; r++)
      S[(ti * 16 + quad * 4 + r) * 81 + tj * 16 + m] = sa[r];
  }
  __syncthreads();

  // causal softmax row-per-thread (scale 1/8), write P bf16 (96-padded)
  if (t < 80) {
    int r = t;
    if (r < 77) {
      float mx = -1e30f;
      for (int j = 0; j <= r; j++) mx = fmaxf(mx, S[r * 81 + j]);
      float sum = 0.f;
      for (int j = 0; j <= r; j++) {
        float e = __expf((S[r * 81 + j] - mx) * 0.125f);
        S[r * 81 + j] = e; sum += e;
      }
      float inv = 1.f / sum;
      for (int j = 0; j < 96; j++)
        u.Ps[r * 96 + j] = (j <= r) ? f2bf(S[r * 81 + j] * inv) : (unsigned short)0;
    } else {
      for (int j = 0; j < 96; j++) u.Ps[r * 96 + j] = 0;
    }
  }
  __syncthreads();

  // O = P @ V : 5x4 tiles, K padded to 96
  for (int idx = wave; idx < 20; idx += 4) {
    int ti = idx >> 2, tj = idx & 3;
    floatx4 oa = {};
    #pragma unroll
    for (int k0 = 0; k0 < 96; k0 += 32) {
      short8 ap = *(const short8*)(u.Ps + (ti * 16 + m) * 96 + k0 + quad * 8);
      short8 bv = *(const short8*)(Vt + (tj * 16 + m) * 96 + k0 + quad * 8);
      oa = __builtin_amdgcn_mfma_f32_16x16x32_bf16(ap, bv, oa, 0, 0, 0);
    }
    #pragma unroll
    for (int r = 0; r < 4; r++) {
      int l = ti * 16 + quad * 4 + r;
      if (l < 77)
        o[((size_t)b * 77 + l) * 768 + hh * 64 + tj * 16 + m] = f2bf(oa[r]);
    }
  }
}

// ---------------- final: per-row normalize, mean over n, renormalize ------
__global__ void reduce_kernel(const float* feats, float* out) {
  __shared__ float red[4];
  int mfig = blockIdx.x;   // 0..7
  int t = threadIdx.x;     // 256
  float a0 = 0.f, a1 = 0.f, a2 = 0.f;
  for (int n = 0; n < 64; n++) {
    const float* fr = feats + ((size_t)mfig * 64 + n) * 768;
    float v0 = fr[t], v1 = fr[t + 256], v2 = fr[t + 512];
    float q = blockReduceSum256(v0 * v0 + v1 * v1 + v2 * v2, red);
    float rn = rsqrtf(q);
    a0 += v0 * rn; a1 += v1 * rn; a2 += v2 * rn;
  }
  float q = blockReduceSum256(a0 * a0 + a1 * a1 + a2 * a2, red);
  float rn = rsqrtf(q);
  out[mfig * 768 + t]       = a0 * rn;
  out[mfig * 768 + t + 256] = a1 * rn;
  out[mfig * 768 + t + 512] = a2 * rn;
}

// ---------------------------------------------------------------------------
extern "C" void kernel_launch(void* const* d_in, const int* in_sizes, int n_in,
                              void* d_out, int out_size, void* d_ws,
                              size_t ws_size, hipStream_t stream) {
  (void)in_sizes; (void)n_in; (void)out_size; (void)ws_size;
  const int*   text      = (const int*)d_in[0];
  const float* visf      = (const float*)d_in[1];
  const float* tok_emb   = (const float*)d_in[2];
  const float* pos_emb   = (const float*)d_in[3];
  const float* ln1_w     = (const float*)d_in[4];
  const float* ln1_b     = (const float*)d_in[5];
  const float* in_w      = (const float*)d_in[6];
  const float* in_b      = (const float*)d_in[7];
  const float* out_w     = (const float*)d_in[8];
  const float* out_b     = (const float*)d_in[9];
  const float* ln2_w     = (const float*)d_in[10];
  const float* ln2_b     = (const float*)d_in[11];
  const float* fc_w      = (const float*)d_in[12];
  const float* fc_b      = (const float*)d_in[13];
  const float* pj_w      = (const float*)d_in[14];
  const float* pj_b      = (const float*)d_in[15];
  const float* lnf_w     = (const float*)d_in[16];
  const float* lnf_b     = (const float*)d_in[17];
  const float* text_proj = (const float*)d_in[18];
  float* out = (float*)d_out;

  char* p = (char*)d_ws;
  auto alloc = [&](size_t bytes) {
    char* q = p; p += (bytes + 255) & ~(size_t)255; return q;
  };
  int* posy = (int*)alloc(64 * 4);
  int* eot  = (int*)alloc(64 * 4);
  float* h            = (float*)alloc((size_t)ROWS * 768 * 4);          // 121 MB
  unsigned short* y   = (unsigned short*)alloc((size_t)ROWS * 768 * 2); // 61 MB
  unsigned short* qkv = (unsigned short*)alloc((size_t)ROWS * 2304 * 2);// 182 MB
  unsigned short* ob  = (unsigned short*)alloc((size_t)ROWS * 768 * 2); // 61 MB
  unsigned short* act = qkv;  // aliases qkv+ob (dead when act is live)
  // per-layer bf16 weight buffer (reused each layer; stream-ordered)
  unsigned short* wqkv = (unsigned short*)alloc((size_t)2304 * 768 * 2);
  unsigned short* wout = (unsigned short*)alloc((size_t)768 * 768 * 2);
  unsigned short* wfc  = (unsigned short*)alloc((size_t)3072 * 768 * 2);
  unsigned short* wpj  = (unsigned short*)alloc((size_t)768 * 3072 * 2);
  unsigned short* wt   = (unsigned short*)alloc((size_t)768 * 768 * 2);
  unsigned short* afin = (unsigned short*)alloc((size_t)512 * 768 * 2);
  float* feats = (float*)alloc((size_t)512 * 768 * 4);

  idx_kernel<<<1, 64, 0, stream>>>(text, posy, eot);
  transT_kernel<<<(768 * 768) / 256, 256, 0, stream>>>(text_proj, wt);
  embed_kernel<<<ROWS, 192, 0, stream>>>(text, visf, tok_emb, pos_emb, posy, h);

  const int NQKV = 2304 * 768, NOUT = 768 * 768, NFC = 3072 * 768;
  const int CVT_BLKS = (NQKV + NOUT + 2 * NFC) / 1024;   // 6912 exact
  for (int l = 0; l < 12; l++) {
    cvt4_kernel<<<CVT_BLKS, 256, 0, stream>>>(
        in_w + (size_t)l * NQKV, out_w + (size_t)l * NOUT,
        fc_w + (size_t)l * NFC, pj_w + (size_t)l * NFC,
        wqkv, wout, wfc, wpj);

    ln4_kernel<<<ROWS / 4, 256, 0, stream>>>(h, ln1_w + l * 768,
                                             ln1_b + l * 768, y);
    gemm256_kernel<0><<<dim3(9, 154), 512, 0, stream>>>(
        y, wqkv, in_b + l * 2304, qkv, nullptr, 768, 2304);
    attn_kernel<<<dim3(512, 12), 256, 0, stream>>>(qkv, ob);
    gemm256_kernel<2><<<dim3(3, 154), 512, 0, stream>>>(
        ob, wout, out_b + l * 768, h, h, 768, 768);
    ln4_kernel<<<ROWS / 4, 256, 0, stream>>>(h, ln2_w + l * 768,
                                             ln2_b + l * 768, y);
    gemm256_kernel<1><<<dim3(12, 154), 512, 0, stream>>>(
        y, wfc, fc_b + l * 3072, act, nullptr, 768, 3072);
    gemm256_kernel<2><<<dim3(3, 154), 512, 0, stream>>>(
        act, wpj, pj_b + l * 768, h, h, 3072, 768);
  }

  gather_ln_kernel<<<512, 256, 0, stream>>>(h, eot, lnf_w, lnf_b, afin);
  gemm256_kernel<3><<<dim3(3, 2), 512, 0, stream>>>(
      afin, wt, nullptr, feats, nullptr, 768, 768);
  reduce_kernel<<<8, 256, 0, stream>>>(feats, out);
}